// Round 6
// baseline (458.517 us; speedup 1.0000x reference)
//
#include <hip/hip_runtime.h>
#include <hip/hip_bf16.h>
#include <stdint.h>

#define IN_CH 64
#define OUT_CH 128

typedef __bf16 bf16x8 __attribute__((ext_vector_type(8)));
typedef float  f32x4  __attribute__((ext_vector_type(4)));

__device__ inline unsigned short f2bf(float f) {
    unsigned u = __float_as_uint(f);
    unsigned r = (u + 0x7fffu + ((u >> 16) & 1u)) >> 16;
    return (unsigned short)r;
}

// Async global->LDS DMA, 16 B per lane. lds dst must be wave-uniform;
// HW writes dst + lane*16. Global src is per-lane.
__device__ inline void gload_lds16(const void* g, void* l) {
    __builtin_amdgcn_global_load_lds(
        (const __attribute__((address_space(1))) unsigned int*)g,
        (__attribute__((address_space(3))) unsigned int*)l, 16, 0, 0);
}

// ---------- fast path ----------

// One prep kernel, three block-ranges:
//  [0, invBlocks)                : inv[] = zero_row; sums = 0
//  [invBlocks, invBlocks+cvtB)   : feats fp32 -> bf16 (+1 zero row)
//  [invBlocks+cvtB, ...)         : W -> wsw, bf16 in MFMA-A fragment order:
//     wsw[((k*16 + g*2 + h)*64 + lane)*8 + j] = bf16(W[k][h*32+(lane>>4)*8+j][g*16+(lane&15)])
__global__ void __launch_bounds__(256) prep_kernel(
    int* __restrict__ inv, int invTot, int zero_row, float* __restrict__ sums,
    const float4* __restrict__ f4, ushort* __restrict__ fb, int n4,
    const float* __restrict__ W, ushort* __restrict__ wsw,
    int invBlocks, int cvtBlocks)
{
    const int b = blockIdx.x;
    const int t = threadIdx.x;
    if (b < invBlocks) {
        int i = b * 256 + t;
        if (i < invTot) inv[i] = zero_row;
        if (b == 0) sums[t] = 0.f;
    } else if (b < invBlocks + cvtBlocks) {
        int i = (b - invBlocks) * 256 + t;
        if (i < n4 + 16) {
            ushort4 o;
            if (i < n4) {
                float4 v = f4[i];
                o.x = f2bf(v.x); o.y = f2bf(v.y); o.z = f2bf(v.z); o.w = f2bf(v.w);
            } else {
                o.x = 0; o.y = 0; o.z = 0; o.w = 0;   // zero row for absent entries
            }
            ((ushort4*)fb)[i] = o;
        }
    } else {
        int i = (b - invBlocks - cvtBlocks) * 256 + t;  // one thread = one fragment chunk
        if (i < 9 * 16 * 64) {
            int lane = i & 63;
            int gh = (i >> 6) & 15;
            int k = i >> 10;
            int half = gh & 1;
            int g = gh >> 1;
            int ch = g * 16 + (lane & 15);
            int in0 = half * 32 + (lane >> 4) * 8;
            ushort v[8];
#pragma unroll
            for (int j = 0; j < 8; ++j)
                v[j] = f2bf(W[((size_t)k * IN_CH + in0 + j) * OUT_CH + ch]);
            *(ushort4*)(wsw + (size_t)i * 8)     = make_ushort4(v[0], v[1], v[2], v[3]);
            *(ushort4*)(wsw + (size_t)i * 8 + 4) = make_ushort4(v[4], v[5], v[6], v[7]);
        }
    }
}

// Inverse rulebook, atomic-free: for fixed k the in->out map of a strided
// conv is injective, so inv[out*9+k] has exactly one writer.
__global__ void __launch_bounds__(256) build_inv_kernel(
    const int* __restrict__ in_idx,
    const int* __restrict__ out_idx,
    const int* __restrict__ mask,
    int* __restrict__ inv,
    int R)
{
    int r = blockIdx.x * 256 + threadIdx.x;
    if (r >= R) return;
    int k = blockIdx.y;
    size_t e = (size_t)k * R + r;
    if (!mask[e]) return;
    inv[(size_t)out_idx[e] * 9 + k] = in_idx[e];
}

// Fused: out[e] = sum_k W[k]^T . fb[inv[e][k]], + fused BN-stat partials.
// Wave = 32 entries x 128 channels. W tiles DMA'd to LDS (double-buffered)
// via global_load_lds; F gathers prefetched DEPTH-2 (3 rotating sets).
// vmcnt FIFO per iteration: [F(k+1):4][W(k+1):4][F(k+2):4] -> counted
// vmcnt(4) leaves F(k+2) in flight while guaranteeing W(k+1)+F(k+1)
// landed. Raw s_barrier (never __syncthreads) inside the loop;
// sched_barrier(0) pins FIFO order so the counts are exact.
__global__ void __launch_bounds__(256, 4) fused_out_kernel(
    const ushort* __restrict__ fb,    // [N_in+1][64] bf16 (last row zeros)
    const ushort* __restrict__ wsw,   // [9][16][64][8] bf16 fragment-order
    const int* __restrict__ inv,      // [n_out][9]
    float* __restrict__ out,          // [n_out][128] fp32
    float* __restrict__ sums,         // [256]
    int n_out, int zero_row)
{
    __shared__ __align__(16) char smraw[32768];       // 2 x 16KB W tiles
    ushort (* __restrict__ ldsW)[8192] = (ushort(*)[8192])smraw;
    float* redS = (float*)smraw;                      // [4][128] (reused after loop)
    float* redQ = (float*)(smraw + 2048);             // [4][128]

    const int lane = threadIdx.x & 63;
    const int w = threadIdx.x >> 6;
    const int col = lane & 15;
    const int quad = lane >> 4;
    const int base = blockIdx.x * 128 + w * 32;
    const int eA = base + col;
    const int eB = base + 16 + col;
    const bool okA = eA < n_out;
    const bool okB = eB < n_out;

    int ivA[9], ivB[9];
    {
        const int* __restrict__ pA = inv + (size_t)(okA ? eA : 0) * 9;
        const int* __restrict__ pB = inv + (size_t)(okB ? eB : 0) * 9;
#pragma unroll
        for (int k = 0; k < 9; ++k) ivA[k] = okA ? pA[k] : zero_row;
#pragma unroll
        for (int k = 0; k < 9; ++k) ivB[k] = okB ? pB[k] : zero_row;
    }
    // Drain the inv loads so every counted vmcnt below is exact.
    asm volatile("s_waitcnt vmcnt(0)" ::: "memory");
    __builtin_amdgcn_sched_barrier(0);

    // Wave's staging quarter of a 16KB tile.
    const int sWave = w * 4096;           // uniform per wave (LDS dst)
    const int sLane = sWave + lane * 16;  // per-lane (global src)

    f32x4 accA[8], accB[8];
#pragma unroll
    for (int g = 0; g < 8; ++g) {
        accA[g] = (f32x4){0.f, 0.f, 0.f, 0.f};
        accB[g] = (f32x4){0.f, 0.f, 0.f, 0.f};
    }

    bf16x8 FA0[3], FA1[3], FB0[3], FB1[3];

    // ---- prologue: DMA W(0) -> lds[0]; gather F(0), F(1) ----
    {
#pragma unroll
        for (int j = 0; j < 4; ++j)
            gload_lds16((const char*)wsw + sLane + j * 1024,
                        smraw + sWave + j * 1024);
        __builtin_amdgcn_sched_barrier(0);
#pragma unroll
        for (int d = 0; d < 2; ++d) {
            const ushort* fa = fb + (size_t)ivA[d] * IN_CH + quad * 8;
            FA0[d] = *(const bf16x8*)fa;
            FA1[d] = *(const bf16x8*)(fa + 32);
            const ushort* fbp = fb + (size_t)ivB[d] * IN_CH + quad * 8;
            FB0[d] = *(const bf16x8*)fbp;
            FB1[d] = *(const bf16x8*)(fbp + 32);
            __builtin_amdgcn_sched_barrier(0);
        }
        // queue: [W(0):4][F(0):4][F(1):4] -> leave the 8 F loads in flight
        asm volatile("s_waitcnt vmcnt(8)" ::: "memory");
        __builtin_amdgcn_s_barrier();
        __builtin_amdgcn_sched_barrier(0);
    }

#pragma unroll
    for (int k = 0; k < 9; ++k) {
        const int cur = k & 1;
        const int nxt = cur ^ 1;
        const int fcur = k % 3;
        const int f2 = (k + 2) % 3;

        // 1. DMA W(k+1) -> lds[nxt] (older than F(k+2) in the FIFO)
        if (k < 8) {
#pragma unroll
            for (int j = 0; j < 4; ++j)
                gload_lds16((const char*)wsw + (size_t)(k + 1) * 16384 + sLane + j * 1024,
                            smraw + nxt * 16384 + sWave + j * 1024);
            __builtin_amdgcn_sched_barrier(0);
        }
        // 2. F(k+2) gathers (youngest; survive the counted wait below)
        if (k < 7) {
            const ushort* fa = fb + (size_t)ivA[k + 2] * IN_CH + quad * 8;
            FA0[f2] = *(const bf16x8*)fa;
            FA1[f2] = *(const bf16x8*)(fa + 32);
            const ushort* fbp = fb + (size_t)ivB[k + 2] * IN_CH + quad * 8;
            FB0[f2] = *(const bf16x8*)fbp;
            FB1[f2] = *(const bf16x8*)(fbp + 32);
            __builtin_amdgcn_sched_barrier(0);
        }

        // 3. compute: W frags from lds[cur], F(k) landed one wait ago
        const ushort* wl = &ldsW[cur][lane * 8];
#pragma unroll
        for (int g = 0; g < 8; ++g) {
            bf16x8 W0 = *(const bf16x8*)(wl + (g * 2 + 0) * 512);
            bf16x8 W1 = *(const bf16x8*)(wl + (g * 2 + 1) * 512);
            accA[g] = __builtin_amdgcn_mfma_f32_16x16x32_bf16(W0, FA0[fcur], accA[g], 0, 0, 0);
            accA[g] = __builtin_amdgcn_mfma_f32_16x16x32_bf16(W1, FA1[fcur], accA[g], 0, 0, 0);
            accB[g] = __builtin_amdgcn_mfma_f32_16x16x32_bf16(W0, FB0[fcur], accB[g], 0, 0, 0);
            accB[g] = __builtin_amdgcn_mfma_f32_16x16x32_bf16(W1, FB1[fcur], accB[g], 0, 0, 0);
        }

        // 4. counted drain: W(k+1)+F(k+1) landed; F(k+2) stays in flight
        if (k < 7) {
            asm volatile("s_waitcnt vmcnt(4)" ::: "memory");
            __builtin_amdgcn_s_barrier();
            __builtin_amdgcn_sched_barrier(0);
        } else if (k == 7) {
            asm volatile("s_waitcnt vmcnt(0)" ::: "memory");  // no F(9) behind W(8)
            __builtin_amdgcn_s_barrier();
            __builtin_amdgcn_sched_barrier(0);
        }
    }

    // Store: lane holds channels g*16 + quad*4 + {0..3} of its entry.
    if (okA) {
        float* __restrict__ rp = out + (size_t)eA * OUT_CH + quad * 4;
#pragma unroll
        for (int g = 0; g < 8; ++g)
            *(f32x4*)(rp + g * 16) = accA[g];
    }
    if (okB) {
        float* __restrict__ rp = out + (size_t)eB * OUT_CH + quad * 4;
#pragma unroll
        for (int g = 0; g < 8; ++g)
            *(f32x4*)(rp + g * 16) = accB[g];
    }

    // BN stats: sum over entries = butterfly over the 16 col-lanes (masks
    // 1..8 stay inside a quad). Invalid entries are exact zeros.
    f32x4 ss[8], qq[8];
#pragma unroll
    for (int g = 0; g < 8; ++g) {
        ss[g] = accA[g] + accB[g];
        qq[g] = accA[g] * accA[g] + accB[g] * accB[g];
    }
#pragma unroll
    for (int m = 1; m <= 8; m <<= 1) {
#pragma unroll
        for (int g = 0; g < 8; ++g) {
#pragma unroll
            for (int j = 0; j < 4; ++j) {
                ss[g][j] += __shfl_xor(ss[g][j], m);
                qq[g][j] += __shfl_xor(qq[g][j], m);
            }
        }
    }

    // LDS region is reused for the reduction: barrier before overwrite.
    __syncthreads();
    if (col == 0) {
#pragma unroll
        for (int g = 0; g < 8; ++g)
#pragma unroll
            for (int j = 0; j < 4; ++j) {
                redS[w * OUT_CH + g * 16 + quad * 4 + j] = ss[g][j];
                redQ[w * OUT_CH + g * 16 + quad * 4 + j] = qq[g][j];
            }
    }
    __syncthreads();
    if (threadIdx.x < OUT_CH) {
        int c = threadIdx.x;
        float a  = redS[c] + redS[OUT_CH + c] + redS[2 * OUT_CH + c] + redS[3 * OUT_CH + c];
        float bq = redQ[c] + redQ[OUT_CH + c] + redQ[2 * OUT_CH + c] + redQ[3 * OUT_CH + c];
        atomicAdd(&sums[c], a);
        atomicAdd(&sums[OUT_CH + c], bq);
    }
}

// y = gamma*(x-mean)*rsqrt(var+eps)+beta, relu; in-place, float4.
__global__ void __launch_bounds__(256) bn_relu_kernel(
    float4* __restrict__ out,
    const float* __restrict__ sums,
    const float* __restrict__ gamma,
    const float* __restrict__ beta,
    int total4, float inv_n)
{
    int idx = blockIdx.x * 256 + threadIdx.x;
    if (idx >= total4) return;
    int c0 = (idx & 31) * 4;
    float4 v = out[idx];
    float r[4] = {v.x, v.y, v.z, v.w};
#pragma unroll
    for (int j = 0; j < 4; ++j) {
        int c = c0 + j;
        float mean = sums[c] * inv_n;
        float var = sums[OUT_CH + c] * inv_n - mean * mean;
        float scale = gamma[c] * rsqrtf(var + 1e-5f);
        float y = (r[j] - mean) * scale + beta[c];
        r[j] = fmaxf(y, 0.0f);
    }
    out[idx] = make_float4(r[0], r[1], r[2], r[3]);
}

// ---------- fallback (atomic scatter) if ws too small ----------

__global__ void __launch_bounds__(256) zero_kernel(float4* __restrict__ out, int n4,
                                                   float* __restrict__ sums) {
    int idx = blockIdx.x * 256 + threadIdx.x;
    if (idx < n4) out[idx] = make_float4(0.f, 0.f, 0.f, 0.f);
    if (blockIdx.x == 0 && threadIdx.x < 2 * OUT_CH) sums[threadIdx.x] = 0.f;
}

__global__ void __launch_bounds__(256) scatter_gemm_kernel(
    const float* __restrict__ feats,
    const float* __restrict__ W,
    const int* __restrict__ in_idx,
    const int* __restrict__ out_idx,
    const int* __restrict__ mask,
    float* __restrict__ acc,
    int R)
{
    const int lane = threadIdx.x & 63;
    const int waveId = threadIdx.x >> 6;
    const int half = waveId & 1;
    const int pair = waveId >> 1;
    const int k = blockIdx.y;
    const int c = half * 64 + lane;

    float wreg[IN_CH];
    const float* __restrict__ wp = W + (size_t)k * IN_CH * OUT_CH + c;
#pragma unroll
    for (int i = 0; i < IN_CH; ++i) wreg[i] = wp[i * OUT_CH];

    const int r0 = blockIdx.x * 128;
    const int rEnd = min(r0 + 128, R);
    const int* __restrict__ maskK = mask + (size_t)k * R;
    const int* __restrict__ inK = in_idx + (size_t)k * R;
    const int* __restrict__ outK = out_idx + (size_t)k * R;

    for (int r = r0 + pair; r < rEnd; r += 2) {
        if (!__builtin_amdgcn_readfirstlane(maskK[r])) continue;
        int in = __builtin_amdgcn_readfirstlane(inK[r]);
        int out = __builtin_amdgcn_readfirstlane(outK[r]);
        const float* __restrict__ f = feats + (size_t)in * IN_CH;
        float s = 0.f, s1 = 0.f;
#pragma unroll
        for (int i = 0; i < IN_CH; i += 2) {
            s = fmaf(wreg[i], f[i], s);
            s1 = fmaf(wreg[i + 1], f[i + 1], s1);
        }
        atomicAdd(acc + (size_t)out * OUT_CH + c, s + s1);
    }
}

__global__ void __launch_bounds__(128) stats_kernel(
    const float* __restrict__ acc,
    float* __restrict__ sums,
    int n_out)
{
    int c = threadIdx.x;
    float s = 0.0f, s2 = 0.0f;
    for (int r = blockIdx.x; r < n_out; r += gridDim.x) {
        float v = acc[(size_t)r * OUT_CH + c];
        s += v;
        s2 += v * v;
    }
    atomicAdd(&sums[c], s);
    atomicAdd(&sums[OUT_CH + c], s2);
}

// ---------- launch ----------

extern "C" void kernel_launch(void* const* d_in, const int* in_sizes, int n_in,
                              void* d_out, int out_size, void* d_ws, size_t ws_size,
                              hipStream_t stream) {
    const float* feats   = (const float*)d_in[0];
    const float* W       = (const float*)d_in[1];
    const float* gamma   = (const float*)d_in[2];
    const float* beta    = (const float*)d_in[3];
    const int*   in_idx  = (const int*)d_in[4];
    const int*   out_idx = (const int*)d_in[5];
    const int*   mask    = (const int*)d_in[6];   // bool stored as int32

    const int R = in_sizes[4] / 9;
    const int n_out = out_size / OUT_CH;
    const int N_in = in_sizes[0] / IN_CH;
    float* acc = (float*)d_out;

    size_t off_inv  = 0;
    size_t sz_inv   = (size_t)n_out * 9 * sizeof(int);
    size_t off_sums = (off_inv + sz_inv + 15) & ~(size_t)15;
    size_t off_fb   = (off_sums + 1024 + 15) & ~(size_t)15;
    size_t off_wsw  = (off_fb + (size_t)(N_in + 1) * IN_CH * 2 + 15) & ~(size_t)15;
    size_t needed   = off_wsw + (size_t)9 * OUT_CH * IN_CH * 2;

    if (ws_size >= needed) {
        int*    inv  = (int*)((char*)d_ws + off_inv);
        float*  sums = (float*)((char*)d_ws + off_sums);
        ushort* fb   = (ushort*)((char*)d_ws + off_fb);
        ushort* wsw  = (ushort*)((char*)d_ws + off_wsw);

        const int invTot = n_out * 9;
        const int n4 = N_in * IN_CH / 4;
        const int invBlocks = (invTot + 255) / 256;
        const int cvtBlocks = (n4 + 16 + 255) / 256;
        const int wswBlocks = (9 * 16 * 64 + 255) / 256;

        prep_kernel<<<invBlocks + cvtBlocks + wswBlocks, 256, 0, stream>>>(
            inv, invTot, N_in, sums,
            (const float4*)feats, fb, n4,
            W, wsw, invBlocks, cvtBlocks);

        dim3 gridB((R + 255) / 256, 9);
        build_inv_kernel<<<gridB, 256, 0, stream>>>(in_idx, out_idx, mask, inv, R);

        fused_out_kernel<<<(n_out + 127) / 128, 256, 0, stream>>>(
            fb, wsw, inv, acc, sums, n_out, N_in);

        int total4 = out_size / 4;
        bn_relu_kernel<<<(total4 + 255) / 256, 256, 0, stream>>>(
            (float4*)acc, sums, gamma, beta, total4, 1.0f / (float)n_out);
    } else {
        float* sums = (float*)d_ws;
        int n4 = out_size / 4;
        zero_kernel<<<(n4 + 255) / 256, 256, 0, stream>>>((float4*)acc, n4, sums);

        dim3 grid((R + 127) / 128, 9);
        scatter_gemm_kernel<<<grid, 256, 0, stream>>>(feats, W, in_idx, out_idx, mask, acc, R);

        stats_kernel<<<2048, 128, 0, stream>>>(acc, sums, n_out);

        int total4 = out_size / 4;
        bn_relu_kernel<<<(total4 + 255) / 256, 256, 0, stream>>>(
            (float4*)acc, sums, gamma, beta, total4, 1.0f / (float)n_out);
    }
}

// Round 8
// 404.525 us; speedup vs baseline: 1.1335x; 1.1335x over previous
//
#include <hip/hip_runtime.h>
#include <hip/hip_bf16.h>
#include <stdint.h>

#define IN_CH 64
#define OUT_CH 128

typedef __bf16 bf16x8 __attribute__((ext_vector_type(8)));
typedef float  f32x4  __attribute__((ext_vector_type(4)));

__device__ inline unsigned short f2bf(float f) {
    unsigned u = __float_as_uint(f);
    unsigned r = (u + 0x7fffu + ((u >> 16) & 1u)) >> 16;
    return (unsigned short)r;
}

// ---------- fast path ----------

// One prep kernel, three block-ranges:
//  [0, invBlocks)                : inv[] = zero_row; sums = 0
//  [invBlocks, invBlocks+cvtB)   : feats fp32 -> bf16 (+1 zero row)
//  [invBlocks+cvtB, ...)         : W -> wsw, bf16 in MFMA-A fragment order:
//     wsw[((k*16 + g*2 + h)*64 + lane)*8 + j] = bf16(W[k][h*32+(lane>>4)*8+j][g*16+(lane&15)])
__global__ void __launch_bounds__(256) prep_kernel(
    int* __restrict__ inv, int invTot, int zero_row, float* __restrict__ sums,
    const float4* __restrict__ f4, ushort* __restrict__ fb, int n4,
    const float* __restrict__ W, ushort* __restrict__ wsw,
    int invBlocks, int cvtBlocks)
{
    const int b = blockIdx.x;
    const int t = threadIdx.x;
    if (b < invBlocks) {
        int i = b * 256 + t;
        if (i < invTot) inv[i] = zero_row;
        if (b == 0) sums[t] = 0.f;
    } else if (b < invBlocks + cvtBlocks) {
        int i = (b - invBlocks) * 256 + t;
        if (i < n4 + 16) {
            ushort4 o;
            if (i < n4) {
                float4 v = f4[i];
                o.x = f2bf(v.x); o.y = f2bf(v.y); o.z = f2bf(v.z); o.w = f2bf(v.w);
            } else {
                o.x = 0; o.y = 0; o.z = 0; o.w = 0;   // zero row for absent entries
            }
            ((ushort4*)fb)[i] = o;
        }
    } else {
        int i = (b - invBlocks - cvtBlocks) * 256 + t;  // one thread = one fragment chunk
        if (i < 9 * 16 * 64) {
            int lane = i & 63;
            int gh = (i >> 6) & 15;
            int k = i >> 10;
            int half = gh & 1;
            int g = gh >> 1;
            int ch = g * 16 + (lane & 15);
            int in0 = half * 32 + (lane >> 4) * 8;
            ushort v[8];
#pragma unroll
            for (int j = 0; j < 8; ++j)
                v[j] = f2bf(W[((size_t)k * IN_CH + in0 + j) * OUT_CH + ch]);
            *(ushort4*)(wsw + (size_t)i * 8)     = make_ushort4(v[0], v[1], v[2], v[3]);
            *(ushort4*)(wsw + (size_t)i * 8 + 4) = make_ushort4(v[4], v[5], v[6], v[7]);
        }
    }
}

// Inverse rulebook, atomic-free: for fixed k the in->out map of a strided
// conv is injective, so inv[out*9+k] has exactly one writer.
__global__ void __launch_bounds__(256) build_inv_kernel(
    const int* __restrict__ in_idx,
    const int* __restrict__ out_idx,
    const int* __restrict__ mask,
    int* __restrict__ inv,
    int R)
{
    int r = blockIdx.x * 256 + threadIdx.x;
    if (r >= R) return;
    int k = blockIdx.y;
    size_t e = (size_t)k * R + r;
    if (!mask[e]) return;
    inv[(size_t)out_idx[e] * 9 + k] = in_idx[e];
}

// Fused: out[e] = sum_k W[k]^T . fb[inv[e][k]], + fused BN-stat partials.
// Wave = 32 entries x 128 channels. ROUND-4 VERIFIED SYNC STRUCTURE:
// W tiles reg-staged into LDS (double-buffered, ds_write + lgkmcnt(0) +
// raw s_barrier); ALL vmcnt management left to the backend, which emits
// exact per-register counted waits (stage-commit waits only on vw; the
// younger F gathers stay in flight). This round adds DEPTH-2 F prefetch
// (3 rotating sets, F(k+2) issued at iteration k) for ~2 iterations of
// latency cover. NO hand vmcnt asm (round-7 lesson: the hand-counted
// global_load_lds protocol miscomputes silently).
__global__ void __launch_bounds__(256, 3) fused_out_kernel(
    const ushort* __restrict__ fb,    // [N_in+1][64] bf16 (last row zeros)
    const ushort* __restrict__ wsw,   // [9][16][64][8] bf16 fragment-order
    const int* __restrict__ inv,      // [n_out][9]
    float* __restrict__ out,          // [n_out][128] fp32
    float* __restrict__ sums,         // [256]
    int n_out, int zero_row)
{
    __shared__ __align__(16) char smraw[32768];       // 2 x 16KB W tiles
    ushort (*ldsW)[8192] = (ushort(*)[8192])smraw;
    float* redS = (float*)smraw;                      // [4][128] (reused after loop)
    float* redQ = (float*)(smraw + 2048);             // [4][128]

    const int lane = threadIdx.x & 63;
    const int w = threadIdx.x >> 6;
    const int col = lane & 15;
    const int quad = lane >> 4;
    const int base = blockIdx.x * 128 + w * 32;
    const int eA = base + col;
    const int eB = base + 16 + col;
    const bool okA = eA < n_out;
    const bool okB = eB < n_out;

    int ivA[9], ivB[9];
    {
        const int* __restrict__ pA = inv + (size_t)(okA ? eA : 0) * 9;
        const int* __restrict__ pB = inv + (size_t)(okB ? eB : 0) * 9;
#pragma unroll
        for (int k = 0; k < 9; ++k) ivA[k] = okA ? pA[k] : zero_row;
#pragma unroll
        for (int k = 0; k < 9; ++k) ivB[k] = okB ? pB[k] : zero_row;
    }

    // Wave's staging quarter of a 16KB tile: bytes [w*4K, w*4K+4K).
    const int soff = w * 4096 + lane * 16;

    f32x4 accA[8], accB[8];
#pragma unroll
    for (int g = 0; g < 8; ++g) {
        accA[g] = (f32x4){0.f, 0.f, 0.f, 0.f};
        accB[g] = (f32x4){0.f, 0.f, 0.f, 0.f};
    }

    bf16x8 FA0[3], FA1[3], FB0[3], FB1[3];

    // ---- prologue: stage W(0) -> lds[0]; gather F(0), F(1) ----
    {
        float4 vw[4];
        const char* src = (const char*)wsw + soff;
#pragma unroll
        for (int j = 0; j < 4; ++j)
            vw[j] = *(const float4*)(src + j * 1024);
        __builtin_amdgcn_sched_barrier(0);
#pragma unroll
        for (int d = 0; d < 2; ++d) {
            const ushort* fa = fb + (size_t)ivA[d] * IN_CH + quad * 8;
            FA0[d] = *(const bf16x8*)fa;
            FA1[d] = *(const bf16x8*)(fa + 32);
            const ushort* fbp = fb + (size_t)ivB[d] * IN_CH + quad * 8;
            FB0[d] = *(const bf16x8*)fbp;
            FB1[d] = *(const bf16x8*)(fbp + 32);
            __builtin_amdgcn_sched_barrier(0);
        }
        // Backend waits vmcnt only for vw here; F(0),F(1) stay in flight.
        char* dst = (char*)&ldsW[0][0] + soff;
#pragma unroll
        for (int j = 0; j < 4; ++j)
            *(float4*)(dst + j * 1024) = vw[j];
        asm volatile("s_waitcnt lgkmcnt(0)" ::: "memory");
        __builtin_amdgcn_s_barrier();
        __builtin_amdgcn_sched_barrier(0);
    }

#pragma unroll
    for (int k = 0; k < 9; ++k) {
        const int cur = k & 1;
        const int nxt = cur ^ 1;
        const int fcur = k % 3;
        const int f2 = (k + 2) % 3;

        // 1. issue stage loads for W(k+1)
        float4 vw[4];
        if (k < 8) {
            const char* src = (const char*)wsw + (size_t)(k + 1) * 16384 + soff;
#pragma unroll
            for (int j = 0; j < 4; ++j)
                vw[j] = *(const float4*)(src + j * 1024);
            __builtin_amdgcn_sched_barrier(0);
        }
        // 2. issue F(k+2) gathers (youngest; backend's counted waits for
        //    vw / F(k) leave these in flight)
        if (k < 7) {
            const ushort* fa = fb + (size_t)ivA[k + 2] * IN_CH + quad * 8;
            FA0[f2] = *(const bf16x8*)fa;
            FA1[f2] = *(const bf16x8*)(fa + 32);
            const ushort* fbp = fb + (size_t)ivB[k + 2] * IN_CH + quad * 8;
            FB0[f2] = *(const bf16x8*)fbp;
            FB1[f2] = *(const bf16x8*)(fbp + 32);
            __builtin_amdgcn_sched_barrier(0);
        }

        // 3. compute: W frags from lds[cur] (lgkm waits), F(k) landed
        const ushort* wl = &ldsW[cur][lane * 8];
#pragma unroll
        for (int g = 0; g < 8; ++g) {
            bf16x8 W0 = *(const bf16x8*)(wl + (g * 2 + 0) * 512);
            bf16x8 W1 = *(const bf16x8*)(wl + (g * 2 + 1) * 512);
            accA[g] = __builtin_amdgcn_mfma_f32_16x16x32_bf16(W0, FA0[fcur], accA[g], 0, 0, 0);
            accA[g] = __builtin_amdgcn_mfma_f32_16x16x32_bf16(W1, FA1[fcur], accA[g], 0, 0, 0);
            accB[g] = __builtin_amdgcn_mfma_f32_16x16x32_bf16(W0, FB0[fcur], accB[g], 0, 0, 0);
            accB[g] = __builtin_amdgcn_mfma_f32_16x16x32_bf16(W1, FB1[fcur], accB[g], 0, 0, 0);
        }

        // 4. commit stage to lds[nxt]; backend waits vmcnt only for vw,
        //    leaving F(k+1),F(k+2) in flight. lgkmcnt(0)+barrier publishes.
        if (k < 8) {
            char* dst = (char*)&ldsW[nxt][0] + soff;
#pragma unroll
            for (int j = 0; j < 4; ++j)
                *(float4*)(dst + j * 1024) = vw[j];
            asm volatile("s_waitcnt lgkmcnt(0)" ::: "memory");
            __builtin_amdgcn_s_barrier();
            __builtin_amdgcn_sched_barrier(0);
        }
    }

    // Store: lane holds channels g*16 + quad*4 + {0..3} of its entry.
    if (okA) {
        float* __restrict__ rp = out + (size_t)eA * OUT_CH + quad * 4;
#pragma unroll
        for (int g = 0; g < 8; ++g)
            *(f32x4*)(rp + g * 16) = accA[g];
    }
    if (okB) {
        float* __restrict__ rp = out + (size_t)eB * OUT_CH + quad * 4;
#pragma unroll
        for (int g = 0; g < 8; ++g)
            *(f32x4*)(rp + g * 16) = accB[g];
    }

    // BN stats: sum over entries = butterfly over the 16 col-lanes (masks
    // 1..8 stay inside a quad). Invalid entries are exact zeros.
    f32x4 ss[8], qq[8];
#pragma unroll
    for (int g = 0; g < 8; ++g) {
        ss[g] = accA[g] + accB[g];
        qq[g] = accA[g] * accA[g] + accB[g] * accB[g];
    }
#pragma unroll
    for (int m = 1; m <= 8; m <<= 1) {
#pragma unroll
        for (int g = 0; g < 8; ++g) {
#pragma unroll
            for (int j = 0; j < 4; ++j) {
                ss[g][j] += __shfl_xor(ss[g][j], m);
                qq[g][j] += __shfl_xor(qq[g][j], m);
            }
        }
    }

    // LDS region is reused for the reduction: full barrier before overwrite.
    __syncthreads();
    if (col == 0) {
#pragma unroll
        for (int g = 0; g < 8; ++g)
#pragma unroll
            for (int j = 0; j < 4; ++j) {
                redS[w * OUT_CH + g * 16 + quad * 4 + j] = ss[g][j];
                redQ[w * OUT_CH + g * 16 + quad * 4 + j] = qq[g][j];
            }
    }
    __syncthreads();
    if (threadIdx.x < OUT_CH) {
        int c = threadIdx.x;
        float a  = redS[c] + redS[OUT_CH + c] + redS[2 * OUT_CH + c] + redS[3 * OUT_CH + c];
        float bq = redQ[c] + redQ[OUT_CH + c] + redQ[2 * OUT_CH + c] + redQ[3 * OUT_CH + c];
        atomicAdd(&sums[c], a);
        atomicAdd(&sums[OUT_CH + c], bq);
    }
}

// y = gamma*(x-mean)*rsqrt(var+eps)+beta, relu; in-place, float4.
__global__ void __launch_bounds__(256) bn_relu_kernel(
    float4* __restrict__ out,
    const float* __restrict__ sums,
    const float* __restrict__ gamma,
    const float* __restrict__ beta,
    int total4, float inv_n)
{
    int idx = blockIdx.x * 256 + threadIdx.x;
    if (idx >= total4) return;
    int c0 = (idx & 31) * 4;
    float4 v = out[idx];
    float r[4] = {v.x, v.y, v.z, v.w};
#pragma unroll
    for (int j = 0; j < 4; ++j) {
        int c = c0 + j;
        float mean = sums[c] * inv_n;
        float var = sums[OUT_CH + c] * inv_n - mean * mean;
        float scale = gamma[c] * rsqrtf(var + 1e-5f);
        float y = (r[j] - mean) * scale + beta[c];
        r[j] = fmaxf(y, 0.0f);
    }
    out[idx] = make_float4(r[0], r[1], r[2], r[3]);
}

// ---------- fallback (atomic scatter) if ws too small ----------

__global__ void __launch_bounds__(256) zero_kernel(float4* __restrict__ out, int n4,
                                                   float* __restrict__ sums) {
    int idx = blockIdx.x * 256 + threadIdx.x;
    if (idx < n4) out[idx] = make_float4(0.f, 0.f, 0.f, 0.f);
    if (blockIdx.x == 0 && threadIdx.x < 2 * OUT_CH) sums[threadIdx.x] = 0.f;
}

__global__ void __launch_bounds__(256) scatter_gemm_kernel(
    const float* __restrict__ feats,
    const float* __restrict__ W,
    const int* __restrict__ in_idx,
    const int* __restrict__ out_idx,
    const int* __restrict__ mask,
    float* __restrict__ acc,
    int R)
{
    const int lane = threadIdx.x & 63;
    const int waveId = threadIdx.x >> 6;
    const int half = waveId & 1;
    const int pair = waveId >> 1;
    const int k = blockIdx.y;
    const int c = half * 64 + lane;

    float wreg[IN_CH];
    const float* __restrict__ wp = W + (size_t)k * IN_CH * OUT_CH + c;
#pragma unroll
    for (int i = 0; i < IN_CH; ++i) wreg[i] = wp[i * OUT_CH];

    const int r0 = blockIdx.x * 128;
    const int rEnd = min(r0 + 128, R);
    const int* __restrict__ maskK = mask + (size_t)k * R;
    const int* __restrict__ inK = in_idx + (size_t)k * R;
    const int* __restrict__ outK = out_idx + (size_t)k * R;

    for (int r = r0 + pair; r < rEnd; r += 2) {
        if (!__builtin_amdgcn_readfirstlane(maskK[r])) continue;
        int in = __builtin_amdgcn_readfirstlane(inK[r]);
        int out = __builtin_amdgcn_readfirstlane(outK[r]);
        const float* __restrict__ f = feats + (size_t)in * IN_CH;
        float s = 0.f, s1 = 0.f;
#pragma unroll
        for (int i = 0; i < IN_CH; i += 2) {
            s = fmaf(wreg[i], f[i], s);
            s1 = fmaf(wreg[i + 1], f[i + 1], s1);
        }
        atomicAdd(acc + (size_t)out * OUT_CH + c, s + s1);
    }
}

__global__ void __launch_bounds__(128) stats_kernel(
    const float* __restrict__ acc,
    float* __restrict__ sums,
    int n_out)
{
    int c = threadIdx.x;
    float s = 0.0f, s2 = 0.0f;
    for (int r = blockIdx.x; r < n_out; r += gridDim.x) {
        float v = acc[(size_t)r * OUT_CH + c];
        s += v;
        s2 += v * v;
    }
    atomicAdd(&sums[c], s);
    atomicAdd(&sums[OUT_CH + c], s2);
}

// ---------- launch ----------

extern "C" void kernel_launch(void* const* d_in, const int* in_sizes, int n_in,
                              void* d_out, int out_size, void* d_ws, size_t ws_size,
                              hipStream_t stream) {
    const float* feats   = (const float*)d_in[0];
    const float* W       = (const float*)d_in[1];
    const float* gamma   = (const float*)d_in[2];
    const float* beta    = (const float*)d_in[3];
    const int*   in_idx  = (const int*)d_in[4];
    const int*   out_idx = (const int*)d_in[5];
    const int*   mask    = (const int*)d_in[6];   // bool stored as int32

    const int R = in_sizes[4] / 9;
    const int n_out = out_size / OUT_CH;
    const int N_in = in_sizes[0] / IN_CH;
    float* acc = (float*)d_out;

    size_t off_inv  = 0;
    size_t sz_inv   = (size_t)n_out * 9 * sizeof(int);
    size_t off_sums = (off_inv + sz_inv + 15) & ~(size_t)15;
    size_t off_fb   = (off_sums + 1024 + 15) & ~(size_t)15;
    size_t off_wsw  = (off_fb + (size_t)(N_in + 1) * IN_CH * 2 + 15) & ~(size_t)15;
    size_t needed   = off_wsw + (size_t)9 * OUT_CH * IN_CH * 2;

    if (ws_size >= needed) {
        int*    inv  = (int*)((char*)d_ws + off_inv);
        float*  sums = (float*)((char*)d_ws + off_sums);
        ushort* fb   = (ushort*)((char*)d_ws + off_fb);
        ushort* wsw  = (ushort*)((char*)d_ws + off_wsw);

        const int invTot = n_out * 9;
        const int n4 = N_in * IN_CH / 4;
        const int invBlocks = (invTot + 255) / 256;
        const int cvtBlocks = (n4 + 16 + 255) / 256;
        const int wswBlocks = (9 * 16 * 64 + 255) / 256;

        prep_kernel<<<invBlocks + cvtBlocks + wswBlocks, 256, 0, stream>>>(
            inv, invTot, N_in, sums,
            (const float4*)feats, fb, n4,
            W, wsw, invBlocks, cvtBlocks);

        dim3 gridB((R + 255) / 256, 9);
        build_inv_kernel<<<gridB, 256, 0, stream>>>(in_idx, out_idx, mask, inv, R);

        fused_out_kernel<<<(n_out + 127) / 128, 256, 0, stream>>>(
            fb, wsw, inv, acc, sums, n_out, N_in);

        int total4 = out_size / 4;
        bn_relu_kernel<<<(total4 + 255) / 256, 256, 0, stream>>>(
            (float4*)acc, sums, gamma, beta, total4, 1.0f / (float)n_out);
    } else {
        float* sums = (float*)d_ws;
        int n4 = out_size / 4;
        zero_kernel<<<(n4 + 255) / 256, 256, 0, stream>>>((float4*)acc, n4, sums);

        dim3 grid((R + 127) / 128, 9);
        scatter_gemm_kernel<<<grid, 256, 0, stream>>>(feats, W, in_idx, out_idx, mask, acc, R);

        stats_kernel<<<2048, 128, 0, stream>>>(acc, sums, n_out);

        int total4 = out_size / 4;
        bn_relu_kernel<<<(total4 + 255) / 256, 256, 0, stream>>>(
            (float4*)acc, sums, gamma, beta, total4, 1.0f / (float)n_out);
    }
}